// Round 5
// baseline (1003.683 us; speedup 1.0000x reference)
//
#include <hip/hip_runtime.h>

typedef unsigned short u16;
typedef __attribute__((ext_vector_type(4))) unsigned short u16x4;
typedef __attribute__((ext_vector_type(8))) short short8;
typedef __attribute__((ext_vector_type(4))) float f32x4;

#define DEV static __device__ __forceinline__

constexpr int NB   = 16;
constexpr int S    = 512;
constexpr int DM   = 4096;
constexpr int NH   = 32;
constexpr int NKV  = 8;
constexpr int HD   = 128;
constexpr int TOK  = NB * S;          // 8192
constexpr int NQKV = 6144;            // 4096 q + 1024 k + 1024 v
constexpr float ATT_SCALE = 0.08838834764831845f;  // 1/sqrt(128)

DEV u16 f2b(float f) {
  union { float f; unsigned u; } v; v.f = f;
  unsigned r = v.u + 0x7fffu + ((v.u >> 16) & 1u);
  return (u16)(r >> 16);
}
DEV float b2f(u16 u) {
  union { unsigned u; float f; } v; v.u = ((unsigned)u) << 16;
  return v.f;
}
DEV void async16(const void* g, void* l) {
  __builtin_amdgcn_global_load_lds(
      (const __attribute__((address_space(1))) unsigned int*)g,
      (__attribute__((address_space(3))) unsigned int*)l, 16, 0, 0);
}

// ---------------- f32 -> bf16 convert (hidden states) ----------------
__global__ void k_cvt_bf16(const float* __restrict__ src, u16* __restrict__ dst) {
  int i = (blockIdx.x * 256 + threadIdx.x) * 4;
  const float4 v = *reinterpret_cast<const float4*>(src + i);
  u16x4 o;
  o[0] = f2b(v.x); o[1] = f2b(v.y); o[2] = f2b(v.z); o[3] = f2b(v.w);
  *reinterpret_cast<u16x4*>(dst + i) = o;
}

// ---------------- weight transpose: src[K=4096][ncols] f32 -> dst[ncols][4096] bf16 ----
__global__ void k_tr_w(const float* __restrict__ src, u16* __restrict__ dst, int ncols) {
  __shared__ float tile[32][33];
  int tx = threadIdx.x, ty = threadIdx.y;
  int n0 = blockIdx.x * 32, k0 = blockIdx.y * 32;
#pragma unroll
  for (int i = 0; i < 32; i += 8)
    tile[ty + i][tx] = src[(size_t)(k0 + ty + i) * ncols + n0 + tx];
  __syncthreads();
#pragma unroll
  for (int i = 0; i < 32; i += 8)
    dst[(size_t)(n0 + ty + i) * 4096 + k0 + tx] = f2b(tile[tx][ty + i]);
}

// ---------------- RoPE cos/sin table per (b,s) ----------------
__global__ void k_rope_tab(const int* __restrict__ pos_ids, float2* __restrict__ tab) {
  int t = blockIdx.x;      // 0..8191
  int j = threadIdx.x;     // 0..63
  float pos = (float)pos_ids[t];
  float inv = expf(-(float)j * 0.21586735246819178f);
  float ang = pos * inv;
  float sv, cv;
  sincosf(ang, &sv, &cv);
  tab[t * 64 + j] = make_float2(cv, sv);
}

// ---------------- fused RMSNorm + RoPE, in-place on qkv (q and k heads) ----------------
__global__ void k_norm_rope(u16* __restrict__ qkv, const float2* __restrict__ tab,
                            const float* __restrict__ qw, const float* __restrict__ kw) {
  int wid  = blockIdx.x * 4 + (threadIdx.x >> 6);
  int lane = threadIdx.x & 63;
  int t  = wid / 40;
  int hh = wid - t * 40;
  bool isq = hh < 32;
  u16* base = qkv + (size_t)t * NQKV + (isq ? hh * 128 : 4096 + (hh - 32) * 128);
  float x1 = b2f(base[lane]);
  float x2 = b2f(base[lane + 64]);
  float ss = x1 * x1 + x2 * x2;
#pragma unroll
  for (int m = 1; m < 64; m <<= 1) ss += __shfl_xor(ss, m, 64);
  float r = rsqrtf(ss * (1.0f / 128.0f) + 1e-6f);
  const float* w = isq ? qw : kw;
  float y1 = x1 * r * w[lane];
  float y2 = x2 * r * w[lane + 64];
  float2 cs = tab[t * 64 + lane];
  float o1 = y1 * cs.x - y2 * cs.y;
  float o2 = y2 * cs.x + y1 * cs.y;
  if (isq) { o1 *= ATT_SCALE; o2 *= ATT_SCALE; }
  base[lane]      = f2b(o1);
  base[lane + 64] = f2b(o2);
}

// ---------------- V transpose: qkv v-cols [b][s][kvh][d] -> vt[b][kvh][d][s] ----------
__global__ void k_tr_v(const u16* __restrict__ qkv, u16* __restrict__ vt) {
  __shared__ u16 tile[32][33];
  int bh = blockIdx.z;           // b*8+kvh
  int b = bh >> 3, kvh = bh & 7;
  int d0 = blockIdx.x * 32, s0 = blockIdx.y * 32;
  int tx = threadIdx.x, ty = threadIdx.y;
#pragma unroll
  for (int i = 0; i < 32; i += 8)
    tile[ty + i][tx] = qkv[(size_t)(b * S + s0 + ty + i) * NQKV + 5120 + kvh * 128 + d0 + tx];
  __syncthreads();
#pragma unroll
  for (int i = 0; i < 32; i += 8)
    vt[((size_t)(bh * 128 + d0 + ty + i)) * S + s0 + tx] = tile[tx][ty + i];
}

// =======================================================================================
// 256x256 8-phase GEMM (T2+T3+T4+T5).
// Round-5 changes: (1) column-major per-XCD block mapping -- each XCD's 32 concurrent
// blocks share ONE B-panel (2MB, L2-resident) and all XCDs sweep the same A k-window
// (L3-resident) => staging hits cache, vmcnt slack suffices; (2) all 4 B-frags held in
// registers -> phase g3 has zero ds_reads (24 reads/tile = minimum).
// =======================================================================================
template <int OUT_BF16>
__global__ __launch_bounds__(512, 2) void k_gemm8(const u16* __restrict__ A,
                                                  const u16* __restrict__ Bm,
                                                  void* __restrict__ Cv,
                                                  int M, int N, int K) {
  __shared__ alignas(16) u16 lds[2][2][256 * 64];   // [buf][A/B][row*64+col]
  const int tid  = threadIdx.x;
  const int lane = tid & 63;
  const int wave = tid >> 6;
  const int r16 = lane & 15, h4 = lane >> 4;
  const int wm = (wave >> 2) * 128, wn = (wave & 3) * 64;

  // bijective XCD chunking, then column-major within each XCD chunk
  const int nbx = N >> 8;
  const int nby = M >> 8;
  const int nwg = nby * nbx;
  const int cpx = nwg >> 3;
  const int wg  = blockIdx.x;
  const int gidx = (wg & 7) * cpx + (wg >> 3);
  const int by = gidx % nby;            // nby = 32 (pow2) -> cheap
  const int bx = gidx / nby;
  const int m0 = by << 8, n0 = bx << 8;

  const int NKT = K >> 6;
  const int NIT = NKT >> 1;

  f32x4 acc[8][4] = {};
  short8 af[4][2];
  short8 bfr[4][2];                     // all 4 B row-frags held across the tile

  auto stage = [&](int s) {
    int ts = s >> 2; if (ts > NKT - 1) ts = NKT - 1;
    const int sel  = s & 3;             // 0:A-h0  1:B-h1  2:A-h1  3:B-h0
    const int isB  = sel & 1;
    const int half = (sel == 1 || sel == 2) ? 1 : 0;
    const u16* G = isB ? Bm : A;
    const int base0 = isB ? n0 : m0;
    u16* lb = &lds[ts & 1][isB][0];
    const int k0 = ts << 6;
#pragma unroll
    for (int j = 0; j < 2; ++j) {
      int c = (j << 9) + tid;           // 0..1023 chunks
      int rl = c >> 3, kcd = c & 7;
      int row = isB ? ((rl & 31) | (half << 5) | ((rl >> 5) << 6))
                    : ((rl & 63) | (half << 6) | ((rl >> 6) << 7));
      int kc = kcd ^ (row & 7);
      async16(G + (size_t)(base0 + row) * K + k0 + (kc << 3),
              lb + row * 64 + (kcd << 3));
    }
  };
  auto ldA = [&](int buf, int mf, int ks) {
    int row = wm + mf * 16 + r16;
    int kc = ((ks << 2) + h4) ^ (r16 & 7);
    return *reinterpret_cast<const short8*>(&lds[buf][0][row * 64 + (kc << 3)]);
  };
  auto ldB = [&](int buf, int nf, int ks) {
    int row = wn + nf * 16 + r16;
    int kc = ((ks << 2) + h4) ^ (r16 & 7);
    return *reinterpret_cast<const short8*>(&lds[buf][1][row * 64 + (kc << 3)]);
  };

#pragma unroll
  for (int s = 0; s < 7; ++s) stage(s);
  asm volatile("s_waitcnt vmcnt(6)" ::: "memory");
  __builtin_amdgcn_s_barrier();

  for (int i = 0; i < NIT; ++i) {
#pragma unroll
    for (int ph = 0; ph < 2; ++ph) {
      const int buf = ph;
#pragma unroll
      for (int g = 0; g < 4; ++g) {
        // (a) ds-read register subtile (g3: zero reads -- B01 still live from g0)
        if (g == 0) {
#pragma unroll
          for (int mf = 0; mf < 4; ++mf)
#pragma unroll
            for (int ks = 0; ks < 2; ++ks) af[mf][ks] = ldA(buf, mf, ks);
#pragma unroll
          for (int nf = 0; nf < 2; ++nf)
#pragma unroll
            for (int ks = 0; ks < 2; ++ks) bfr[nf][ks] = ldB(buf, nf, ks);
        } else if (g == 1) {
#pragma unroll
          for (int nf = 0; nf < 2; ++nf)
#pragma unroll
            for (int ks = 0; ks < 2; ++ks) bfr[2 + nf][ks] = ldB(buf, 2 + nf, ks);
        } else if (g == 2) {
#pragma unroll
          for (int mf = 0; mf < 4; ++mf)
#pragma unroll
            for (int ks = 0; ks < 2; ++ks) af[mf][ks] = ldA(buf, 4 + mf, ks);
        }
        // (b) stage one half-tile prefetch
        stage(7 + i * 8 + ph * 4 + g);
        if (g == 0) asm volatile("s_waitcnt lgkmcnt(8)" ::: "memory");
        // (c) barrier, (d) LDS drain
        __builtin_amdgcn_s_barrier();
        asm volatile("s_waitcnt lgkmcnt(0)" ::: "memory");
        __builtin_amdgcn_sched_barrier(0);
        // (e) MFMA cluster: one C-quadrant x K=64
        __builtin_amdgcn_s_setprio(1);
        const int mo = (g >= 2) ? 4 : 0;
        const int no = (g == 1 || g == 2) ? 2 : 0;
#pragma unroll
        for (int mf = 0; mf < 4; ++mf)
#pragma unroll
          for (int nf = 0; nf < 2; ++nf)
#pragma unroll
            for (int ks = 0; ks < 2; ++ks)
              acc[mo + mf][no + nf] = __builtin_amdgcn_mfma_f32_16x16x32_bf16(
                  af[mf][ks], bfr[no + nf][ks], acc[mo + mf][no + nf], 0, 0, 0);
        __builtin_amdgcn_s_setprio(0);
        // (f) counted vmcnt once per K-tile
        if (g == 3) asm volatile("s_waitcnt vmcnt(6)" ::: "memory");
        __builtin_amdgcn_s_barrier();
      }
    }
  }

  if (OUT_BF16) {
    u16* C = (u16*)Cv;
#pragma unroll
    for (int mf = 0; mf < 8; ++mf)
#pragma unroll
      for (int nf = 0; nf < 4; ++nf)
#pragma unroll
        for (int r = 0; r < 4; ++r) {
          size_t row = m0 + wm + mf * 16 + h4 * 4 + r;
          size_t col = n0 + wn + nf * 16 + r16;
          C[row * N + col] = f2b(acc[mf][nf][r]);
        }
  } else {
    float* C = (float*)Cv;
#pragma unroll
    for (int mf = 0; mf < 8; ++mf)
#pragma unroll
      for (int nf = 0; nf < 4; ++nf)
#pragma unroll
        for (int r = 0; r < 4; ++r) {
          size_t row = m0 + wm + mf * 16 + h4 * 4 + r;
          size_t col = n0 + wn + nf * 16 + r16;
          C[row * N + col] = acc[mf][nf][r];
        }
  }
}

// =======================================================================================
// Flash attention v3 (round-4, unchanged): GQA-shared K/V staging + pipelined dbuf.
// =======================================================================================
__global__ __launch_bounds__(256) void k_attn(const u16* __restrict__ qkv,
                                              const u16* __restrict__ vt,
                                              u16* __restrict__ out) {
  __shared__ alignas(16) u16 Klds[2][64 * 128];   // [buf][key][d] swizzled
  __shared__ alignas(16) u16 Vlds[2][128 * 64];   // [buf][d][key] swizzled
  __shared__ alignas(16) u16 Plds[4][2][16 * 64]; // [wave][rf][qrow][key] swizzled
  const int qt = blockIdx.x, kvh = blockIdx.y, b = blockIdx.z;
  const int tid = threadIdx.x, lane = tid & 63, wave = tid >> 6;
  const int r16 = lane & 15, h4 = lane >> 4;
  const int h = kvh * 4 + wave;
  const int qr0 = qt * 32;

  auto stageKV = [&](int t, int buf) {
    const int k0 = t << 6;
    const u16* kg = qkv + (size_t)(b * S + k0) * NQKV + 4096 + kvh * 128;
#pragma unroll
    for (int it = 0; it < 4; ++it) {
      int c = tid + (it << 8);            // 0..1023 chunks of 16B
      int key = c >> 4, c8 = c & 15;
      int jc = c8 ^ (key & 7);
      async16(kg + (size_t)key * NQKV + jc * 8, &Klds[buf][c * 8]);
    }
    const u16* vg = vt + (size_t)(b * 8 + kvh) * 128 * S + k0;
#pragma unroll
    for (int it = 0; it < 4; ++it) {
      int c = tid + (it << 8);
      int d = c >> 3, c8 = c & 7;
      int jc = c8 ^ (d & 7);
      async16(vg + (size_t)d * S + jc * 8, &Vlds[buf][c * 8]);
    }
  };
  auto ldK = [&](int buf, int f, int s4) {
    int key = f * 16 + r16;
    int idx = (key * 128 + s4 * 32 + h4 * 8) ^ ((key & 7) << 3);
    return *reinterpret_cast<const short8*>(&Klds[buf][idx]);
  };
  auto ldV = [&](int buf, int df, int ks) {
    int d = df * 16 + r16;
    int idx = (d * 64 + ks * 32 + h4 * 8) ^ ((d & 7) << 3);
    return *reinterpret_cast<const short8*>(&Vlds[buf][idx]);
  };

  short8 qf[2][4];
#pragma unroll
  for (int rf = 0; rf < 2; ++rf) {
    const u16* qrow = qkv + (size_t)(b * S + qr0 + rf * 16 + r16) * NQKV + h * 128 + h4 * 8;
#pragma unroll
    for (int s4 = 0; s4 < 4; ++s4)
      qf[rf][s4] = *reinterpret_cast<const short8*>(qrow + s4 * 32);
  }

  float mrow[2][4], lrow[2][4];
  f32x4 o[2][8] = {};
#pragma unroll
  for (int rf = 0; rf < 2; ++rf)
#pragma unroll
    for (int r = 0; r < 4; ++r) { mrow[rf][r] = -INFINITY; lrow[rf][r] = 0.f; }

  const int ntiles = (qt >> 1) + 1;
  stageKV(0, 0);
  __syncthreads();

  for (int t = 0; t < ntiles; ++t) {
    const int buf = t & 1;
    if (t + 1 < ntiles) stageKV(t + 1, buf ^ 1);
    const int k0 = t << 6;
    const bool diag = (t == ntiles - 1);
    int fa0 = 4, fa1 = 4;
    if (diag) {
      fa0 = ((qr0 - k0 + 15) >> 4) + 1; if (fa0 > 4) fa0 = 4;
      fa1 = ((qr0 - k0 + 31) >> 4) + 1; if (fa1 > 4) fa1 = 4;
    }
    const int ks_act = (fa1 + 1) >> 1;

    f32x4 sacc[2][4] = {};
#pragma unroll
    for (int f = 0; f < 4; ++f) {
      if (f < fa1) {
        short8 kf[4];
#pragma unroll
        for (int s4 = 0; s4 < 4; ++s4) kf[s4] = ldK(buf, f, s4);
#pragma unroll
        for (int s4 = 0; s4 < 4; ++s4) {
          if (f < fa0)
            sacc[0][f] = __builtin_amdgcn_mfma_f32_16x16x32_bf16(qf[0][s4], kf[s4], sacc[0][f], 0, 0, 0);
          sacc[1][f] = __builtin_amdgcn_mfma_f32_16x16x32_bf16(qf[1][s4], kf[s4], sacc[1][f], 0, 0, 0);
        }
      }
    }
    if (diag) {
#pragma unroll
      for (int rf = 0; rf < 2; ++rf)
#pragma unroll
        for (int f = 0; f < 4; ++f)
#pragma unroll
          for (int r = 0; r < 4; ++r) {
            int key = k0 + f * 16 + r16;
            int row = qr0 + rf * 16 + h4 * 4 + r;
            if (key > row) sacc[rf][f][r] = -1e30f;
          }
    }
    float fac[2][4];
#pragma unroll
    for (int rf = 0; rf < 2; ++rf)
#pragma unroll
      for (int r = 0; r < 4; ++r) {
        float mx = fmaxf(fmaxf(sacc[rf][0][r], sacc[rf][1][r]),
                         fmaxf(sacc[rf][2][r], sacc[rf][3][r]));
#pragma unroll
        for (int m = 1; m < 16; m <<= 1) mx = fmaxf(mx, __shfl_xor(mx, m, 64));
        float mn = fmaxf(mrow[rf][r], mx);
        fac[rf][r] = __expf(mrow[rf][r] - mn);
        mrow[rf][r] = mn;
        float psum = 0.f;
#pragma unroll
        for (int f = 0; f < 4; ++f) {
          float p = __expf(sacc[rf][f][r] - mn);
          sacc[rf][f][r] = p;
          psum += p;
        }
#pragma unroll
        for (int m = 1; m < 16; m <<= 1) psum += __shfl_xor(psum, m, 64);
        lrow[rf][r] = lrow[rf][r] * fac[rf][r] + psum;
      }
#pragma unroll
    for (int rf = 0; rf < 2; ++rf)
#pragma unroll
      for (int df = 0; df < 8; ++df)
#pragma unroll
        for (int r = 0; r < 4; ++r) o[rf][df][r] *= fac[rf][r];

#pragma unroll
    for (int rf = 0; rf < 2; ++rf)
#pragma unroll
      for (int f = 0; f < 4; ++f)
#pragma unroll
        for (int r = 0; r < 4; ++r) {
          int row = h4 * 4 + r;
          int idx = (row * 64 + f * 16 + r16) ^ ((row & 7) << 3);
          Plds[wave][rf][idx] = f2b(sacc[rf][f][r]);
        }
    short8 pf[2][2];
#pragma unroll
    for (int rf = 0; rf < 2; ++rf)
#pragma unroll
      for (int ks = 0; ks < 2; ++ks)
        if (ks < ks_act) {
          int idx = (r16 * 64 + ks * 32 + h4 * 8) ^ ((r16 & 7) << 3);
          pf[rf][ks] = *reinterpret_cast<const short8*>(&Plds[wave][rf][idx]);
        }
#pragma unroll
    for (int df = 0; df < 8; ++df)
#pragma unroll
      for (int ks = 0; ks < 2; ++ks)
        if (ks < ks_act) {
          short8 vf = ldV(buf, df, ks);
#pragma unroll
          for (int rf = 0; rf < 2; ++rf)
            o[rf][df] = __builtin_amdgcn_mfma_f32_16x16x32_bf16(pf[rf][ks], vf, o[rf][df], 0, 0, 0);
        }
    __syncthreads();
  }

#pragma unroll
  for (int rf = 0; rf < 2; ++rf)
#pragma unroll
    for (int df = 0; df < 8; ++df)
#pragma unroll
      for (int r = 0; r < 4; ++r) {
        int row = qr0 + rf * 16 + h4 * 4 + r;
        float val = o[rf][df][r] / lrow[rf][r];
        out[(size_t)(b * S + row) * 4096 + h * 128 + df * 16 + r16] = f2b(val);
      }
}

// ---------------------------------------------------------------------------------------
extern "C" void kernel_launch(void* const* d_in, const int* in_sizes, int n_in,
                              void* d_out, int out_size, void* d_ws, size_t ws_size,
                              hipStream_t stream) {
  const float* hs  = (const float*)d_in[0];
  const int*   pos = (const int*)d_in[1];
  const float* Wq  = (const float*)d_in[2];
  const float* Wk  = (const float*)d_in[3];
  const float* Wv  = (const float*)d_in[4];
  const float* Wo  = (const float*)d_in[5];
  const float* qnw = (const float*)d_in[6];
  const float* knw = (const float*)d_in[7];

  char* ws = (char*)d_ws;
  u16*   X    = (u16*)(ws);
  u16*   WT   = (u16*)(ws + 67108864);
  u16*   QKV  = (u16*)(ws + 117440512);
  u16*   VT   = (u16*)(ws + 218103808);
  float2* TAB = (float2*)(ws + 234881024);
  u16*   ATTN = X;
  u16*   WOT  = WT;

  // 1. hidden f32 -> bf16
  k_cvt_bf16<<<(TOK * DM / 4) / 256, 256, 0, stream>>>(hs, X);
  // 2. weight transposes into fused [6144][4096] operand
  k_tr_w<<<dim3(128, 128), dim3(32, 8), 0, stream>>>(Wq, WT, 4096);
  k_tr_w<<<dim3(32, 128),  dim3(32, 8), 0, stream>>>(Wk, WT + (size_t)4096 * 4096, 1024);
  k_tr_w<<<dim3(32, 128),  dim3(32, 8), 0, stream>>>(Wv, WT + (size_t)5120 * 4096, 1024);
  // 3. RoPE table
  k_rope_tab<<<TOK, 64, 0, stream>>>(pos, TAB);
  // 4. QKV GEMM (8-phase 256^2): [8192,4096] x [6144,4096]^T -> bf16 qkv
  k_gemm8<1><<<(8192 / 256) * (6144 / 256), 512, 0, stream>>>(X, WT, QKV, 8192, 6144, 4096);
  // 5. RMSNorm + RoPE in place (q scaled by 1/sqrt(128))
  k_norm_rope<<<TOK * 40 / 4, 256, 0, stream>>>(QKV, TAB, qnw, knw);
  // 6. V transpose to [b][kvh][d][s]
  k_tr_v<<<dim3(4, 16, 128), dim3(32, 8), 0, stream>>>(QKV, VT);
  // 7. Wo transpose (reuses WT region -- safe: after gemm1 in stream order)
  k_tr_w<<<dim3(128, 128), dim3(32, 8), 0, stream>>>(Wo, WOT, 4096);
  // 8. attention -> ATTN (reuses X region -- safe: after gemm1)
  k_attn<<<dim3(16, 8, 16), 256, 0, stream>>>(QKV, VT, ATTN);
  // 9. output projection (8-phase 256^2) -> d_out (f32)
  k_gemm8<0><<<(8192 / 256) * (4096 / 256), 512, 0, stream>>>(ATTN, WOT, d_out, 8192, 4096, 4096);
}

// Round 6
// 915.455 us; speedup vs baseline: 1.0964x; 1.0964x over previous
//
#include <hip/hip_runtime.h>

typedef unsigned short u16;
typedef __attribute__((ext_vector_type(4))) unsigned short u16x4;
typedef __attribute__((ext_vector_type(8))) short short8;
typedef __attribute__((ext_vector_type(4))) float f32x4;

#define DEV static __device__ __forceinline__

constexpr int NB   = 16;
constexpr int S    = 512;
constexpr int DM   = 4096;
constexpr int NH   = 32;
constexpr int NKV  = 8;
constexpr int HD   = 128;
constexpr int TOK  = NB * S;          // 8192
constexpr int NQKV = 6144;            // 4096 q + 1024 k + 1024 v
constexpr float ATT_SCALE = 0.08838834764831845f;  // 1/sqrt(128)

DEV u16 f2b(float f) {
  union { float f; unsigned u; } v; v.f = f;
  unsigned r = v.u + 0x7fffu + ((v.u >> 16) & 1u);
  return (u16)(r >> 16);
}
DEV float b2f(u16 u) {
  union { unsigned u; float f; } v; v.u = ((unsigned)u) << 16;
  return v.f;
}
DEV void async16(const void* g, void* l) {
  __builtin_amdgcn_global_load_lds(
      (const __attribute__((address_space(1))) unsigned int*)g,
      (__attribute__((address_space(3))) unsigned int*)l, 16, 0, 0);
}

// ---------------- f32 -> bf16 convert (hidden states) ----------------
__global__ void k_cvt_bf16(const float* __restrict__ src, u16* __restrict__ dst) {
  int i = (blockIdx.x * 256 + threadIdx.x) * 4;
  const float4 v = *reinterpret_cast<const float4*>(src + i);
  u16x4 o;
  o[0] = f2b(v.x); o[1] = f2b(v.y); o[2] = f2b(v.z); o[3] = f2b(v.w);
  *reinterpret_cast<u16x4*>(dst + i) = o;
}

// ---------------- weight transpose: src[K=4096][ncols] f32 -> dst[ncols][4096] bf16 ----
__global__ void k_tr_w(const float* __restrict__ src, u16* __restrict__ dst, int ncols) {
  __shared__ float tile[32][33];
  int tx = threadIdx.x, ty = threadIdx.y;
  int n0 = blockIdx.x * 32, k0 = blockIdx.y * 32;
#pragma unroll
  for (int i = 0; i < 32; i += 8)
    tile[ty + i][tx] = src[(size_t)(k0 + ty + i) * ncols + n0 + tx];
  __syncthreads();
#pragma unroll
  for (int i = 0; i < 32; i += 8)
    dst[(size_t)(n0 + ty + i) * 4096 + k0 + tx] = f2b(tile[tx][ty + i]);
}

// ---------------- RoPE cos/sin table per (b,s) ----------------
__global__ void k_rope_tab(const int* __restrict__ pos_ids, float2* __restrict__ tab) {
  int t = blockIdx.x;      // 0..8191
  int j = threadIdx.x;     // 0..63
  float pos = (float)pos_ids[t];
  float inv = expf(-(float)j * 0.21586735246819178f);
  float ang = pos * inv;
  float sv, cv;
  sincosf(ang, &sv, &cv);
  tab[t * 64 + j] = make_float2(cv, sv);
}

// ---------------- fused RMSNorm + RoPE, in-place on qkv (q and k heads) ----------------
__global__ void k_norm_rope(u16* __restrict__ qkv, const float2* __restrict__ tab,
                            const float* __restrict__ qw, const float* __restrict__ kw) {
  int wid  = blockIdx.x * 4 + (threadIdx.x >> 6);
  int lane = threadIdx.x & 63;
  int t  = wid / 40;
  int hh = wid - t * 40;
  bool isq = hh < 32;
  u16* base = qkv + (size_t)t * NQKV + (isq ? hh * 128 : 4096 + (hh - 32) * 128);
  float x1 = b2f(base[lane]);
  float x2 = b2f(base[lane + 64]);
  float ss = x1 * x1 + x2 * x2;
#pragma unroll
  for (int m = 1; m < 64; m <<= 1) ss += __shfl_xor(ss, m, 64);
  float r = rsqrtf(ss * (1.0f / 128.0f) + 1e-6f);
  const float* w = isq ? qw : kw;
  float y1 = x1 * r * w[lane];
  float y2 = x2 * r * w[lane + 64];
  float2 cs = tab[t * 64 + lane];
  float o1 = y1 * cs.x - y2 * cs.y;
  float o2 = y2 * cs.x + y1 * cs.y;
  if (isq) { o1 *= ATT_SCALE; o2 *= ATT_SCALE; }
  base[lane]      = f2b(o1);
  base[lane + 64] = f2b(o2);
}

// ---------------- V transpose: qkv v-cols [b][s][kvh][d] -> vt[b][kvh][d][s] ----------
__global__ void k_tr_v(const u16* __restrict__ qkv, u16* __restrict__ vt) {
  __shared__ u16 tile[32][33];
  int bh = blockIdx.z;           // b*8+kvh
  int b = bh >> 3, kvh = bh & 7;
  int d0 = blockIdx.x * 32, s0 = blockIdx.y * 32;
  int tx = threadIdx.x, ty = threadIdx.y;
#pragma unroll
  for (int i = 0; i < 32; i += 8)
    tile[ty + i][tx] = qkv[(size_t)(b * S + s0 + ty + i) * NQKV + 5120 + kvh * 128 + d0 + tx];
  __syncthreads();
#pragma unroll
  for (int i = 0; i < 32; i += 8)
    vt[((size_t)(bh * 128 + d0 + ty + i)) * S + s0 + tx] = tile[tx][ty + i];
}

// =======================================================================================
// 256x256 8-phase GEMM (T2+T3+T4+T5) -- byte-identical to round 5.
// =======================================================================================
template <int OUT_BF16>
__global__ __launch_bounds__(512, 2) void k_gemm8(const u16* __restrict__ A,
                                                  const u16* __restrict__ Bm,
                                                  void* __restrict__ Cv,
                                                  int M, int N, int K) {
  __shared__ alignas(16) u16 lds[2][2][256 * 64];   // [buf][A/B][row*64+col]
  const int tid  = threadIdx.x;
  const int lane = tid & 63;
  const int wave = tid >> 6;
  const int r16 = lane & 15, h4 = lane >> 4;
  const int wm = (wave >> 2) * 128, wn = (wave & 3) * 64;

  const int nbx = N >> 8;
  const int nby = M >> 8;
  const int nwg = nby * nbx;
  const int cpx = nwg >> 3;
  const int wg  = blockIdx.x;
  const int gidx = (wg & 7) * cpx + (wg >> 3);
  const int by = gidx % nby;
  const int bx = gidx / nby;
  const int m0 = by << 8, n0 = bx << 8;

  const int NKT = K >> 6;
  const int NIT = NKT >> 1;

  f32x4 acc[8][4] = {};
  short8 af[4][2];
  short8 bfr[4][2];

  auto stage = [&](int s) {
    int ts = s >> 2; if (ts > NKT - 1) ts = NKT - 1;
    const int sel  = s & 3;
    const int isB  = sel & 1;
    const int half = (sel == 1 || sel == 2) ? 1 : 0;
    const u16* G = isB ? Bm : A;
    const int base0 = isB ? n0 : m0;
    u16* lb = &lds[ts & 1][isB][0];
    const int k0 = ts << 6;
#pragma unroll
    for (int j = 0; j < 2; ++j) {
      int c = (j << 9) + tid;
      int rl = c >> 3, kcd = c & 7;
      int row = isB ? ((rl & 31) | (half << 5) | ((rl >> 5) << 6))
                    : ((rl & 63) | (half << 6) | ((rl >> 6) << 7));
      int kc = kcd ^ (row & 7);
      async16(G + (size_t)(base0 + row) * K + k0 + (kc << 3),
              lb + row * 64 + (kcd << 3));
    }
  };
  auto ldA = [&](int buf, int mf, int ks) {
    int row = wm + mf * 16 + r16;
    int kc = ((ks << 2) + h4) ^ (r16 & 7);
    return *reinterpret_cast<const short8*>(&lds[buf][0][row * 64 + (kc << 3)]);
  };
  auto ldB = [&](int buf, int nf, int ks) {
    int row = wn + nf * 16 + r16;
    int kc = ((ks << 2) + h4) ^ (r16 & 7);
    return *reinterpret_cast<const short8*>(&lds[buf][1][row * 64 + (kc << 3)]);
  };

#pragma unroll
  for (int s = 0; s < 7; ++s) stage(s);
  asm volatile("s_waitcnt vmcnt(6)" ::: "memory");
  __builtin_amdgcn_s_barrier();

  for (int i = 0; i < NIT; ++i) {
#pragma unroll
    for (int ph = 0; ph < 2; ++ph) {
      const int buf = ph;
#pragma unroll
      for (int g = 0; g < 4; ++g) {
        if (g == 0) {
#pragma unroll
          for (int mf = 0; mf < 4; ++mf)
#pragma unroll
            for (int ks = 0; ks < 2; ++ks) af[mf][ks] = ldA(buf, mf, ks);
#pragma unroll
          for (int nf = 0; nf < 2; ++nf)
#pragma unroll
            for (int ks = 0; ks < 2; ++ks) bfr[nf][ks] = ldB(buf, nf, ks);
        } else if (g == 1) {
#pragma unroll
          for (int nf = 0; nf < 2; ++nf)
#pragma unroll
            for (int ks = 0; ks < 2; ++ks) bfr[2 + nf][ks] = ldB(buf, 2 + nf, ks);
        } else if (g == 2) {
#pragma unroll
          for (int mf = 0; mf < 4; ++mf)
#pragma unroll
            for (int ks = 0; ks < 2; ++ks) af[mf][ks] = ldA(buf, 4 + mf, ks);
        }
        stage(7 + i * 8 + ph * 4 + g);
        if (g == 0) asm volatile("s_waitcnt lgkmcnt(8)" ::: "memory");
        __builtin_amdgcn_s_barrier();
        asm volatile("s_waitcnt lgkmcnt(0)" ::: "memory");
        __builtin_amdgcn_sched_barrier(0);
        __builtin_amdgcn_s_setprio(1);
        const int mo = (g >= 2) ? 4 : 0;
        const int no = (g == 1 || g == 2) ? 2 : 0;
#pragma unroll
        for (int mf = 0; mf < 4; ++mf)
#pragma unroll
          for (int nf = 0; nf < 2; ++nf)
#pragma unroll
            for (int ks = 0; ks < 2; ++ks)
              acc[mo + mf][no + nf] = __builtin_amdgcn_mfma_f32_16x16x32_bf16(
                  af[mf][ks], bfr[no + nf][ks], acc[mo + mf][no + nf], 0, 0, 0);
        __builtin_amdgcn_s_setprio(0);
        if (g == 3) asm volatile("s_waitcnt vmcnt(6)" ::: "memory");
        __builtin_amdgcn_s_barrier();
      }
    }
  }

  if (OUT_BF16) {
    u16* C = (u16*)Cv;
#pragma unroll
    for (int mf = 0; mf < 8; ++mf)
#pragma unroll
      for (int nf = 0; nf < 4; ++nf)
#pragma unroll
        for (int r = 0; r < 4; ++r) {
          size_t row = m0 + wm + mf * 16 + h4 * 4 + r;
          size_t col = n0 + wn + nf * 16 + r16;
          C[row * N + col] = f2b(acc[mf][nf][r]);
        }
  } else {
    float* C = (float*)Cv;
#pragma unroll
    for (int mf = 0; mf < 8; ++mf)
#pragma unroll
      for (int nf = 0; nf < 4; ++nf)
#pragma unroll
        for (int r = 0; r < 4; ++r) {
          size_t row = m0 + wm + mf * 16 + h4 * 4 + r;
          size_t col = n0 + wn + nf * 16 + r16;
          C[row * N + col] = acc[mf][nf][r];
        }
  }
}

// =======================================================================================
// Flash attention v4: SWAPPED-OPERAND MFMA (T12 prereq).
//   QK^T computed as mfma(K, Q)  -> S^T frag: col(lane&15) = q-row, regs = keys.
//     => softmax row-reduce = 16 in-reg ops + 2 shfl_xor (masks 16,32), m/l scalar per rf.
//   PV computed as mfma(V^T, P^T) -> O^T frag: col = q-row, regs = d.
//     => rescale is lane-uniform; epilogue packs u16x4 stores.
// Staging/double-buffer/barrier structure identical to round 4/5 (proven).
// Grid (qt=16, kvh=8, b=16), 256 thr = 4 waves; wave w = head kvh*4+w, 32 q-rows.
// =======================================================================================
__global__ __launch_bounds__(256) void k_attn(const u16* __restrict__ qkv,
                                              const u16* __restrict__ vt,
                                              u16* __restrict__ out) {
  __shared__ alignas(16) u16 Klds[2][64 * 128];   // [buf][key][d] swizzled
  __shared__ alignas(16) u16 Vlds[2][128 * 64];   // [buf][d][key] swizzled
  __shared__ alignas(16) u16 Plds[4][2][16 * 64]; // [wave][rf][q(16)][key(64)] swizzled
  const int qt = blockIdx.x, kvh = blockIdx.y, b = blockIdx.z;
  const int tid = threadIdx.x, lane = tid & 63, wave = tid >> 6;
  const int r16 = lane & 15, h4 = lane >> 4;
  const int h = kvh * 4 + wave;
  const int qr0 = qt * 32;

  auto stageKV = [&](int t, int buf) {
    const int k0 = t << 6;
    const u16* kg = qkv + (size_t)(b * S + k0) * NQKV + 4096 + kvh * 128;
#pragma unroll
    for (int it = 0; it < 4; ++it) {
      int c = tid + (it << 8);            // 0..1023 chunks of 16B
      int key = c >> 4, c8 = c & 15;
      int jc = c8 ^ (key & 7);
      async16(kg + (size_t)key * NQKV + jc * 8, &Klds[buf][c * 8]);
    }
    const u16* vg = vt + (size_t)(b * 8 + kvh) * 128 * S + k0;
#pragma unroll
    for (int it = 0; it < 4; ++it) {
      int c = tid + (it << 8);
      int d = c >> 3, c8 = c & 7;
      int jc = c8 ^ (d & 7);
      async16(vg + (size_t)d * S + jc * 8, &Vlds[buf][c * 8]);
    }
  };
  auto ldK = [&](int buf, int f, int s4) {   // A-frag: row = key, kchunk = h4
    int key = f * 16 + r16;
    int idx = (key * 128 + s4 * 32 + h4 * 8) ^ ((key & 7) << 3);
    return *reinterpret_cast<const short8*>(&Klds[buf][idx]);
  };
  auto ldV = [&](int buf, int df, int ks) {  // A-frag: row = d, kchunk(keys) = h4
    int d = df * 16 + r16;
    int idx = (d * 64 + ks * 32 + h4 * 8) ^ ((d & 7) << 3);
    return *reinterpret_cast<const short8*>(&Vlds[buf][idx]);
  };

  // Q fragments as B-operand: col = q-row (r16), kchunk = h4. Same loads as before.
  short8 qf[2][4];
#pragma unroll
  for (int rf = 0; rf < 2; ++rf) {
    const u16* qrow = qkv + (size_t)(b * S + qr0 + rf * 16 + r16) * NQKV + h * 128 + h4 * 8;
#pragma unroll
    for (int s4 = 0; s4 < 4; ++s4)
      qf[rf][s4] = *reinterpret_cast<const short8*>(qrow + s4 * 32);
  }

  float mrow[2] = {-INFINITY, -INFINITY};
  float lrow[2] = {0.f, 0.f};
  f32x4 o[2][8] = {};    // O^T frags: o[rf][df], col = q-row, regs = d-sub

  const int ntiles = (qt >> 1) + 1;
  stageKV(0, 0);
  __syncthreads();

  for (int t = 0; t < ntiles; ++t) {
    const int buf = t & 1;
    if (t + 1 < ntiles) stageKV(t + 1, buf ^ 1);
    const int k0 = t << 6;
    const bool diag = (t == ntiles - 1);
    int fa0 = 4, fa1 = 4;
    if (diag) {
      fa0 = ((qr0 - k0 + 15) >> 4) + 1; if (fa0 > 4) fa0 = 4;
      fa1 = ((qr0 - k0 + 31) >> 4) + 1; if (fa1 > 4) fa1 = 4;
    }
    const int ks_act = (fa1 + 1) >> 1;

    // S^T = K Q^T : sacc[rf][f] cols = q-rows, regs = keys (f*16 + h4*4 + r)
    f32x4 sacc[2][4] = {};
#pragma unroll
    for (int f = 0; f < 4; ++f) {
      if (f < fa1) {
        short8 kf[4];
#pragma unroll
        for (int s4 = 0; s4 < 4; ++s4) kf[s4] = ldK(buf, f, s4);
#pragma unroll
        for (int s4 = 0; s4 < 4; ++s4) {
          if (f < fa0)
            sacc[0][f] = __builtin_amdgcn_mfma_f32_16x16x32_bf16(kf[s4], qf[0][s4], sacc[0][f], 0, 0, 0);
          sacc[1][f] = __builtin_amdgcn_mfma_f32_16x16x32_bf16(kf[s4], qf[1][s4], sacc[1][f], 0, 0, 0);
        }
      }
    }
    // causal mask (all frags incl. skipped ones: they become exp()=0)
    if (diag) {
#pragma unroll
      for (int rf = 0; rf < 2; ++rf)
#pragma unroll
        for (int f = 0; f < 4; ++f)
#pragma unroll
          for (int r = 0; r < 4; ++r) {
            int key = k0 + f * 16 + h4 * 4 + r;
            int row = qr0 + rf * 16 + r16;
            if (key > row) sacc[rf][f][r] = -1e30f;
          }
    }
    // online softmax: keys are in-lane -> 16 in-reg ops + 2 shfl per rf
    float fac[2];
#pragma unroll
    for (int rf = 0; rf < 2; ++rf) {
      float mx = sacc[rf][0][0];
#pragma unroll
      for (int f = 0; f < 4; ++f)
#pragma unroll
        for (int r = 0; r < 4; ++r) mx = fmaxf(mx, sacc[rf][f][r]);
      mx = fmaxf(mx, __shfl_xor(mx, 16, 64));
      mx = fmaxf(mx, __shfl_xor(mx, 32, 64));
      float mn = fmaxf(mrow[rf], mx);
      fac[rf] = __expf(mrow[rf] - mn);
      mrow[rf] = mn;
      float psum = 0.f;
#pragma unroll
      for (int f = 0; f < 4; ++f)
#pragma unroll
        for (int r = 0; r < 4; ++r) {
          float p = __expf(sacc[rf][f][r] - mn);
          sacc[rf][f][r] = p;
          psum += p;
        }
      psum += __shfl_xor(psum, 16, 64);
      psum += __shfl_xor(psum, 32, 64);
      lrow[rf] = lrow[rf] * fac[rf] + psum;
#pragma unroll
      for (int df = 0; df < 8; ++df)
#pragma unroll
        for (int r = 0; r < 4; ++r) o[rf][df][r] *= fac[rf];
    }

    // P^T -> per-wave LDS: [q=r16][key], swizzled (2-way max on write)
#pragma unroll
    for (int rf = 0; rf < 2; ++rf)
#pragma unroll
      for (int f = 0; f < 4; ++f)
#pragma unroll
        for (int r = 0; r < 4; ++r) {
          int key = f * 16 + h4 * 4 + r;
          int idx = r16 * 64 + (key ^ ((r16 & 7) << 3));
          Plds[wave][rf][idx] = f2b(sacc[rf][f][r]);
        }
    // P^T B-frags: col = q = r16, keys ks*32 + h4*8 .. +8 (b128, swizzle-aligned)
    short8 pf[2][2];
#pragma unroll
    for (int rf = 0; rf < 2; ++rf)
#pragma unroll
      for (int ks = 0; ks < 2; ++ks)
        if (ks < ks_act) {
          int idx = r16 * 64 + ((ks * 32 + h4 * 8) ^ ((r16 & 7) << 3));
          pf[rf][ks] = *reinterpret_cast<const short8*>(&Plds[wave][rf][idx]);
        }
    // O^T += V^T P^T
#pragma unroll
    for (int df = 0; df < 8; ++df)
#pragma unroll
      for (int ks = 0; ks < 2; ++ks)
        if (ks < ks_act) {
          short8 vf = ldV(buf, df, ks);
#pragma unroll
          for (int rf = 0; rf < 2; ++rf)
            o[rf][df] = __builtin_amdgcn_mfma_f32_16x16x32_bf16(vf, pf[rf][ks], o[rf][df], 0, 0, 0);
        }
    __syncthreads();
  }

  // epilogue: lane owns q-row r16 (per rf); d = df*16 + h4*4 + r -> packed u16x4 stores
#pragma unroll
  for (int rf = 0; rf < 2; ++rf) {
    float rinv = 1.0f / lrow[rf];
    int row = qr0 + rf * 16 + r16;
    u16* orow = out + (size_t)(b * S + row) * 4096 + h * 128;
#pragma unroll
    for (int df = 0; df < 8; ++df) {
      u16x4 pk;
#pragma unroll
      for (int r = 0; r < 4; ++r) pk[r] = f2b(o[rf][df][r] * rinv);
      *reinterpret_cast<u16x4*>(orow + df * 16 + h4 * 4) = pk;
    }
  }
}

// ---------------------------------------------------------------------------------------
extern "C" void kernel_launch(void* const* d_in, const int* in_sizes, int n_in,
                              void* d_out, int out_size, void* d_ws, size_t ws_size,
                              hipStream_t stream) {
  const float* hs  = (const float*)d_in[0];
  const int*   pos = (const int*)d_in[1];
  const float* Wq  = (const float*)d_in[2];
  const float* Wk  = (const float*)d_in[3];
  const float* Wv  = (const float*)d_in[4];
  const float* Wo  = (const float*)d_in[5];
  const float* qnw = (const float*)d_in[6];
  const float* knw = (const float*)d_in[7];

  char* ws = (char*)d_ws;
  u16*   X    = (u16*)(ws);
  u16*   WT   = (u16*)(ws + 67108864);
  u16*   QKV  = (u16*)(ws + 117440512);
  u16*   VT   = (u16*)(ws + 218103808);
  float2* TAB = (float2*)(ws + 234881024);
  u16*   ATTN = X;
  u16*   WOT  = WT;

  // 1. hidden f32 -> bf16
  k_cvt_bf16<<<(TOK * DM / 4) / 256, 256, 0, stream>>>(hs, X);
  // 2. weight transposes into fused [6144][4096] operand
  k_tr_w<<<dim3(128, 128), dim3(32, 8), 0, stream>>>(Wq, WT, 4096);
  k_tr_w<<<dim3(32, 128),  dim3(32, 8), 0, stream>>>(Wk, WT + (size_t)4096 * 4096, 1024);
  k_tr_w<<<dim3(32, 128),  dim3(32, 8), 0, stream>>>(Wv, WT + (size_t)5120 * 4096, 1024);
  // 3. RoPE table
  k_rope_tab<<<TOK, 64, 0, stream>>>(pos, TAB);
  // 4. QKV GEMM (8-phase 256^2): [8192,4096] x [6144,4096]^T -> bf16 qkv
  k_gemm8<1><<<(8192 / 256) * (6144 / 256), 512, 0, stream>>>(X, WT, QKV, 8192, 6144, 4096);
  // 5. RMSNorm + RoPE in place (q scaled by 1/sqrt(128))
  k_norm_rope<<<TOK * 40 / 4, 256, 0, stream>>>(QKV, TAB, qnw, knw);
  // 6. V transpose to [b][kvh][d][s]
  k_tr_v<<<dim3(4, 16, 128), dim3(32, 8), 0, stream>>>(QKV, VT);
  // 7. Wo transpose (reuses WT region -- safe: after gemm1 in stream order)
  k_tr_w<<<dim3(128, 128), dim3(32, 8), 0, stream>>>(Wo, WOT, 4096);
  // 8. attention -> ATTN (reuses X region -- safe: after gemm1)
  k_attn<<<dim3(16, 8, 16), 256, 0, stream>>>(QKV, VT, ATTN);
  // 9. output projection (8-phase 256^2) -> d_out (f32)
  k_gemm8<0><<<(8192 / 256) * (4096 / 256), 512, 0, stream>>>(ATTN, WOT, d_out, 8192, 4096, 4096);
}

// Round 7
// 908.063 us; speedup vs baseline: 1.1053x; 1.0081x over previous
//
#include <hip/hip_runtime.h>

typedef unsigned short u16;
typedef __attribute__((ext_vector_type(4))) unsigned short u16x4;
typedef __attribute__((ext_vector_type(8))) short short8;
typedef __attribute__((ext_vector_type(4))) float f32x4;

#define DEV static __device__ __forceinline__

constexpr int NB   = 16;
constexpr int S    = 512;
constexpr int DM   = 4096;
constexpr int NH   = 32;
constexpr int NKV  = 8;
constexpr int HD   = 128;
constexpr int TOK  = NB * S;          // 8192
constexpr int NQKV = 6144;            // 4096 q + 1024 k + 1024 v
constexpr float ATT_SCALE = 0.08838834764831845f;  // 1/sqrt(128)

DEV u16 f2b(float f) {
  union { float f; unsigned u; } v; v.f = f;
  unsigned r = v.u + 0x7fffu + ((v.u >> 16) & 1u);
  return (u16)(r >> 16);
}
DEV float b2f(u16 u) {
  union { unsigned u; float f; } v; v.u = ((unsigned)u) << 16;
  return v.f;
}
DEV void async16(const void* g, void* l) {
  __builtin_amdgcn_global_load_lds(
      (const __attribute__((address_space(1))) unsigned int*)g,
      (__attribute__((address_space(3))) unsigned int*)l, 16, 0, 0);
}

// ---------------- f32 -> bf16 convert (hidden states) ----------------
__global__ void k_cvt_bf16(const float* __restrict__ src, u16* __restrict__ dst) {
  int i = (blockIdx.x * 256 + threadIdx.x) * 4;
  const float4 v = *reinterpret_cast<const float4*>(src + i);
  u16x4 o;
  o[0] = f2b(v.x); o[1] = f2b(v.y); o[2] = f2b(v.z); o[3] = f2b(v.w);
  *reinterpret_cast<u16x4*>(dst + i) = o;
}

// ---------------- weight transpose: src[K=4096][ncols] f32 -> dst[ncols][4096] bf16 ----
__global__ void k_tr_w(const float* __restrict__ src, u16* __restrict__ dst, int ncols) {
  __shared__ float tile[32][33];
  int tx = threadIdx.x, ty = threadIdx.y;
  int n0 = blockIdx.x * 32, k0 = blockIdx.y * 32;
#pragma unroll
  for (int i = 0; i < 32; i += 8)
    tile[ty + i][tx] = src[(size_t)(k0 + ty + i) * ncols + n0 + tx];
  __syncthreads();
#pragma unroll
  for (int i = 0; i < 32; i += 8)
    dst[(size_t)(n0 + ty + i) * 4096 + k0 + tx] = f2b(tile[tx][ty + i]);
}

// ---------------- RoPE cos/sin table per (b,s) ----------------
__global__ void k_rope_tab(const int* __restrict__ pos_ids, float2* __restrict__ tab) {
  int t = blockIdx.x;      // 0..8191
  int j = threadIdx.x;     // 0..63
  float pos = (float)pos_ids[t];
  float inv = expf(-(float)j * 0.21586735246819178f);
  float ang = pos * inv;
  float sv, cv;
  sincosf(ang, &sv, &cv);
  tab[t * 64 + j] = make_float2(cv, sv);
}

// ---------------- fused RMSNorm + RoPE, in-place on qkv (q and k heads) ----------------
__global__ void k_norm_rope(u16* __restrict__ qkv, const float2* __restrict__ tab,
                            const float* __restrict__ qw, const float* __restrict__ kw) {
  int wid  = blockIdx.x * 4 + (threadIdx.x >> 6);
  int lane = threadIdx.x & 63;
  int t  = wid / 40;
  int hh = wid - t * 40;
  bool isq = hh < 32;
  u16* base = qkv + (size_t)t * NQKV + (isq ? hh * 128 : 4096 + (hh - 32) * 128);
  float x1 = b2f(base[lane]);
  float x2 = b2f(base[lane + 64]);
  float ss = x1 * x1 + x2 * x2;
#pragma unroll
  for (int m = 1; m < 64; m <<= 1) ss += __shfl_xor(ss, m, 64);
  float r = rsqrtf(ss * (1.0f / 128.0f) + 1e-6f);
  const float* w = isq ? qw : kw;
  float y1 = x1 * r * w[lane];
  float y2 = x2 * r * w[lane + 64];
  float2 cs = tab[t * 64 + lane];
  float o1 = y1 * cs.x - y2 * cs.y;
  float o2 = y2 * cs.x + y1 * cs.y;
  if (isq) { o1 *= ATT_SCALE; o2 *= ATT_SCALE; }
  base[lane]      = f2b(o1);
  base[lane + 64] = f2b(o2);
}

// ---------------- V transpose: qkv v-cols [b][s][kvh][d] -> vt[b][kvh][d][s] ----------
__global__ void k_tr_v(const u16* __restrict__ qkv, u16* __restrict__ vt) {
  __shared__ u16 tile[32][33];
  int bh = blockIdx.z;           // b*8+kvh
  int b = bh >> 3, kvh = bh & 7;
  int d0 = blockIdx.x * 32, s0 = blockIdx.y * 32;
  int tx = threadIdx.x, ty = threadIdx.y;
#pragma unroll
  for (int i = 0; i < 32; i += 8)
    tile[ty + i][tx] = qkv[(size_t)(b * S + s0 + ty + i) * NQKV + 5120 + kvh * 128 + d0 + tx];
  __syncthreads();
#pragma unroll
  for (int i = 0; i < 32; i += 8)
    vt[((size_t)(bh * 128 + d0 + ty + i)) * S + s0 + tx] = tile[tx][ty + i];
}

// =======================================================================================
// 256x256 8-phase GEMM (T2+T3+T4+T5).
// Round-7 change: removed per-phase lgkmcnt(8)/lgkmcnt(0)/sched_barrier(0). The ds_reads
// are compiler-generated loads, so the compiler inserts fine-grained lgkmcnt(N) per MFMA
// operand (m97 evidence) and can overlap remaining reads with the MFMA cluster. Cross-
// tile reordering is still blocked by the vmcnt(6) asm ("memory" clobber) at g3; each
// LDS buffer is stable for the whole tile, so within-tile motion is safe.
// =======================================================================================
template <int OUT_BF16>
__global__ __launch_bounds__(512, 2) void k_gemm8(const u16* __restrict__ A,
                                                  const u16* __restrict__ Bm,
                                                  void* __restrict__ Cv,
                                                  int M, int N, int K) {
  __shared__ alignas(16) u16 lds[2][2][256 * 64];   // [buf][A/B][row*64+col]
  const int tid  = threadIdx.x;
  const int lane = tid & 63;
  const int wave = tid >> 6;
  const int r16 = lane & 15, h4 = lane >> 4;
  const int wm = (wave >> 2) * 128, wn = (wave & 3) * 64;

  const int nbx = N >> 8;
  const int nby = M >> 8;
  const int nwg = nby * nbx;
  const int cpx = nwg >> 3;
  const int wg  = blockIdx.x;
  const int gidx = (wg & 7) * cpx + (wg >> 3);
  const int by = gidx % nby;
  const int bx = gidx / nby;
  const int m0 = by << 8, n0 = bx << 8;

  const int NKT = K >> 6;
  const int NIT = NKT >> 1;

  f32x4 acc[8][4] = {};
  short8 af[4][2];
  short8 bfr[4][2];

  auto stage = [&](int s) {
    int ts = s >> 2; if (ts > NKT - 1) ts = NKT - 1;
    const int sel  = s & 3;               // 0:A-h0  1:B-h1  2:A-h1  3:B-h0
    const int isB  = sel & 1;
    const int half = (sel == 1 || sel == 2) ? 1 : 0;
    const u16* G = isB ? Bm : A;
    const int base0 = isB ? n0 : m0;
    u16* lb = &lds[ts & 1][isB][0];
    const int k0 = ts << 6;
#pragma unroll
    for (int j = 0; j < 2; ++j) {
      int c = (j << 9) + tid;             // 0..1023 chunks
      int rl = c >> 3, kcd = c & 7;
      int row = isB ? ((rl & 31) | (half << 5) | ((rl >> 5) << 6))
                    : ((rl & 63) | (half << 6) | ((rl >> 6) << 7));
      int kc = kcd ^ (row & 7);
      async16(G + (size_t)(base0 + row) * K + k0 + (kc << 3),
              lb + row * 64 + (kcd << 3));
    }
  };
  auto ldA = [&](int buf, int mf, int ks) {
    int row = wm + mf * 16 + r16;
    int kc = ((ks << 2) + h4) ^ (r16 & 7);
    return *reinterpret_cast<const short8*>(&lds[buf][0][row * 64 + (kc << 3)]);
  };
  auto ldB = [&](int buf, int nf, int ks) {
    int row = wn + nf * 16 + r16;
    int kc = ((ks << 2) + h4) ^ (r16 & 7);
    return *reinterpret_cast<const short8*>(&lds[buf][1][row * 64 + (kc << 3)]);
  };

#pragma unroll
  for (int s = 0; s < 7; ++s) stage(s);
  asm volatile("s_waitcnt vmcnt(6)" ::: "memory");
  __builtin_amdgcn_s_barrier();

  for (int i = 0; i < NIT; ++i) {
#pragma unroll
    for (int ph = 0; ph < 2; ++ph) {
      const int buf = ph;
#pragma unroll
      for (int g = 0; g < 4; ++g) {
        // (a) ds-read register subtile (compiler inserts fine-grained lgkmcnt)
        if (g == 0) {
#pragma unroll
          for (int mf = 0; mf < 4; ++mf)
#pragma unroll
            for (int ks = 0; ks < 2; ++ks) af[mf][ks] = ldA(buf, mf, ks);
#pragma unroll
          for (int nf = 0; nf < 2; ++nf)
#pragma unroll
            for (int ks = 0; ks < 2; ++ks) bfr[nf][ks] = ldB(buf, nf, ks);
        } else if (g == 1) {
#pragma unroll
          for (int nf = 0; nf < 2; ++nf)
#pragma unroll
            for (int ks = 0; ks < 2; ++ks) bfr[2 + nf][ks] = ldB(buf, 2 + nf, ks);
        } else if (g == 2) {
#pragma unroll
          for (int mf = 0; mf < 4; ++mf)
#pragma unroll
            for (int ks = 0; ks < 2; ++ks) af[mf][ks] = ldA(buf, 4 + mf, ks);
        }
        // (b) stage one half-tile prefetch
        stage(7 + i * 8 + ph * 4 + g);
        // (c) phase barrier
        __builtin_amdgcn_s_barrier();
        // (d) MFMA cluster: one C-quadrant x K=64
        __builtin_amdgcn_s_setprio(1);
        const int mo = (g >= 2) ? 4 : 0;
        const int no = (g == 1 || g == 2) ? 2 : 0;
#pragma unroll
        for (int mf = 0; mf < 4; ++mf)
#pragma unroll
          for (int nf = 0; nf < 2; ++nf)
#pragma unroll
            for (int ks = 0; ks < 2; ++ks)
              acc[mo + mf][no + nf] = __builtin_amdgcn_mfma_f32_16x16x32_bf16(
                  af[mf][ks], bfr[no + nf][ks], acc[mo + mf][no + nf], 0, 0, 0);
        __builtin_amdgcn_s_setprio(0);
        // (e) counted vmcnt once per K-tile (collective via following barrier)
        if (g == 3) asm volatile("s_waitcnt vmcnt(6)" ::: "memory");
        __builtin_amdgcn_s_barrier();
      }
    }
  }

  if (OUT_BF16) {
    u16* C = (u16*)Cv;
#pragma unroll
    for (int mf = 0; mf < 8; ++mf)
#pragma unroll
      for (int nf = 0; nf < 4; ++nf)
#pragma unroll
        for (int r = 0; r < 4; ++r) {
          size_t row = m0 + wm + mf * 16 + h4 * 4 + r;
          size_t col = n0 + wn + nf * 16 + r16;
          C[row * N + col] = f2b(acc[mf][nf][r]);
        }
  } else {
    float* C = (float*)Cv;
#pragma unroll
    for (int mf = 0; mf < 8; ++mf)
#pragma unroll
      for (int nf = 0; nf < 4; ++nf)
#pragma unroll
        for (int r = 0; r < 4; ++r) {
          size_t row = m0 + wm + mf * 16 + h4 * 4 + r;
          size_t col = n0 + wn + nf * 16 + r16;
          C[row * N + col] = acc[mf][nf][r];
        }
  }
}

// =======================================================================================
// Flash attention v4 (round-6, unchanged): swapped-operand MFMA, GQA-shared staging.
// =======================================================================================
__global__ __launch_bounds__(256) void k_attn(const u16* __restrict__ qkv,
                                              const u16* __restrict__ vt,
                                              u16* __restrict__ out) {
  __shared__ alignas(16) u16 Klds[2][64 * 128];   // [buf][key][d] swizzled
  __shared__ alignas(16) u16 Vlds[2][128 * 64];   // [buf][d][key] swizzled
  __shared__ alignas(16) u16 Plds[4][2][16 * 64]; // [wave][rf][q(16)][key(64)] swizzled
  const int qt = blockIdx.x, kvh = blockIdx.y, b = blockIdx.z;
  const int tid = threadIdx.x, lane = tid & 63, wave = tid >> 6;
  const int r16 = lane & 15, h4 = lane >> 4;
  const int h = kvh * 4 + wave;
  const int qr0 = qt * 32;

  auto stageKV = [&](int t, int buf) {
    const int k0 = t << 6;
    const u16* kg = qkv + (size_t)(b * S + k0) * NQKV + 4096 + kvh * 128;
#pragma unroll
    for (int it = 0; it < 4; ++it) {
      int c = tid + (it << 8);            // 0..1023 chunks of 16B
      int key = c >> 4, c8 = c & 15;
      int jc = c8 ^ (key & 7);
      async16(kg + (size_t)key * NQKV + jc * 8, &Klds[buf][c * 8]);
    }
    const u16* vg = vt + (size_t)(b * 8 + kvh) * 128 * S + k0;
#pragma unroll
    for (int it = 0; it < 4; ++it) {
      int c = tid + (it << 8);
      int d = c >> 3, c8 = c & 7;
      int jc = c8 ^ (d & 7);
      async16(vg + (size_t)d * S + jc * 8, &Vlds[buf][c * 8]);
    }
  };
  auto ldK = [&](int buf, int f, int s4) {   // A-frag: row = key, kchunk = h4
    int key = f * 16 + r16;
    int idx = (key * 128 + s4 * 32 + h4 * 8) ^ ((key & 7) << 3);
    return *reinterpret_cast<const short8*>(&Klds[buf][idx]);
  };
  auto ldV = [&](int buf, int df, int ks) {  // A-frag: row = d, kchunk(keys) = h4
    int d = df * 16 + r16;
    int idx = (d * 64 + ks * 32 + h4 * 8) ^ ((d & 7) << 3);
    return *reinterpret_cast<const short8*>(&Vlds[buf][idx]);
  };

  // Q fragments as B-operand: col = q-row (r16), kchunk = h4.
  short8 qf[2][4];
#pragma unroll
  for (int rf = 0; rf < 2; ++rf) {
    const u16* qrow = qkv + (size_t)(b * S + qr0 + rf * 16 + r16) * NQKV + h * 128 + h4 * 8;
#pragma unroll
    for (int s4 = 0; s4 < 4; ++s4)
      qf[rf][s4] = *reinterpret_cast<const short8*>(qrow + s4 * 32);
  }

  float mrow[2] = {-INFINITY, -INFINITY};
  float lrow[2] = {0.f, 0.f};
  f32x4 o[2][8] = {};    // O^T frags: o[rf][df], col = q-row, regs = d-sub

  const int ntiles = (qt >> 1) + 1;
  stageKV(0, 0);
  __syncthreads();

  for (int t = 0; t < ntiles; ++t) {
    const int buf = t & 1;
    if (t + 1 < ntiles) stageKV(t + 1, buf ^ 1);
    const int k0 = t << 6;
    const bool diag = (t == ntiles - 1);
    int fa0 = 4, fa1 = 4;
    if (diag) {
      fa0 = ((qr0 - k0 + 15) >> 4) + 1; if (fa0 > 4) fa0 = 4;
      fa1 = ((qr0 - k0 + 31) >> 4) + 1; if (fa1 > 4) fa1 = 4;
    }
    const int ks_act = (fa1 + 1) >> 1;

    // S^T = K Q^T : sacc[rf][f] cols = q-rows, regs = keys (f*16 + h4*4 + r)
    f32x4 sacc[2][4] = {};
#pragma unroll
    for (int f = 0; f < 4; ++f) {
      if (f < fa1) {
        short8 kf[4];
#pragma unroll
        for (int s4 = 0; s4 < 4; ++s4) kf[s4] = ldK(buf, f, s4);
#pragma unroll
        for (int s4 = 0; s4 < 4; ++s4) {
          if (f < fa0)
            sacc[0][f] = __builtin_amdgcn_mfma_f32_16x16x32_bf16(kf[s4], qf[0][s4], sacc[0][f], 0, 0, 0);
          sacc[1][f] = __builtin_amdgcn_mfma_f32_16x16x32_bf16(kf[s4], qf[1][s4], sacc[1][f], 0, 0, 0);
        }
      }
    }
    // causal mask (all frags incl. skipped ones: they become exp()=0)
    if (diag) {
#pragma unroll
      for (int rf = 0; rf < 2; ++rf)
#pragma unroll
        for (int f = 0; f < 4; ++f)
#pragma unroll
          for (int r = 0; r < 4; ++r) {
            int key = k0 + f * 16 + h4 * 4 + r;
            int row = qr0 + rf * 16 + r16;
            if (key > row) sacc[rf][f][r] = -1e30f;
          }
    }
    // online softmax: keys are in-lane -> 16 in-reg ops + 2 shfl per rf
    float fac[2];
#pragma unroll
    for (int rf = 0; rf < 2; ++rf) {
      float mx = sacc[rf][0][0];
#pragma unroll
      for (int f = 0; f < 4; ++f)
#pragma unroll
        for (int r = 0; r < 4; ++r) mx = fmaxf(mx, sacc[rf][f][r]);
      mx = fmaxf(mx, __shfl_xor(mx, 16, 64));
      mx = fmaxf(mx, __shfl_xor(mx, 32, 64));
      float mn = fmaxf(mrow[rf], mx);
      fac[rf] = __expf(mrow[rf] - mn);
      mrow[rf] = mn;
      float psum = 0.f;
#pragma unroll
      for (int f = 0; f < 4; ++f)
#pragma unroll
        for (int r = 0; r < 4; ++r) {
          float p = __expf(sacc[rf][f][r] - mn);
          sacc[rf][f][r] = p;
          psum += p;
        }
      psum += __shfl_xor(psum, 16, 64);
      psum += __shfl_xor(psum, 32, 64);
      lrow[rf] = lrow[rf] * fac[rf] + psum;
#pragma unroll
      for (int df = 0; df < 8; ++df)
#pragma unroll
        for (int r = 0; r < 4; ++r) o[rf][df][r] *= fac[rf];
    }

    // P^T -> per-wave LDS: [q=r16][key], swizzled
#pragma unroll
    for (int rf = 0; rf < 2; ++rf)
#pragma unroll
      for (int f = 0; f < 4; ++f)
#pragma unroll
        for (int r = 0; r < 4; ++r) {
          int key = f * 16 + h4 * 4 + r;
          int idx = r16 * 64 + (key ^ ((r16 & 7) << 3));
          Plds[wave][rf][idx] = f2b(sacc[rf][f][r]);
        }
    // P^T B-frags: col = q = r16, keys ks*32 + h4*8 .. +8
    short8 pf[2][2];
#pragma unroll
    for (int rf = 0; rf < 2; ++rf)
#pragma unroll
      for (int ks = 0; ks < 2; ++ks)
        if (ks < ks_act) {
          int idx = r16 * 64 + ((ks * 32 + h4 * 8) ^ ((r16 & 7) << 3));
          pf[rf][ks] = *reinterpret_cast<const short8*>(&Plds[wave][rf][idx]);
        }
    // O^T += V^T P^T
#pragma unroll
    for (int df = 0; df < 8; ++df)
#pragma unroll
      for (int ks = 0; ks < 2; ++ks)
        if (ks < ks_act) {
          short8 vf = ldV(buf, df, ks);
#pragma unroll
          for (int rf = 0; rf < 2; ++rf)
            o[rf][df] = __builtin_amdgcn_mfma_f32_16x16x32_bf16(vf, pf[rf][ks], o[rf][df], 0, 0, 0);
        }
    __syncthreads();
  }

  // epilogue: lane owns q-row r16 (per rf); packed u16x4 stores
#pragma unroll
  for (int rf = 0; rf < 2; ++rf) {
    float rinv = 1.0f / lrow[rf];
    int row = qr0 + rf * 16 + r16;
    u16* orow = out + (size_t)(b * S + row) * 4096 + h * 128;
#pragma unroll
    for (int df = 0; df < 8; ++df) {
      u16x4 pk;
#pragma unroll
      for (int r = 0; r < 4; ++r) pk[r] = f2b(o[rf][df][r] * rinv);
      *reinterpret_cast<u16x4*>(orow + df * 16 + h4 * 4) = pk;
    }
  }
}

// ---------------------------------------------------------------------------------------
extern "C" void kernel_launch(void* const* d_in, const int* in_sizes, int n_in,
                              void* d_out, int out_size, void* d_ws, size_t ws_size,
                              hipStream_t stream) {
  const float* hs  = (const float*)d_in[0];
  const int*   pos = (const int*)d_in[1];
  const float* Wq  = (const float*)d_in[2];
  const float* Wk  = (const float*)d_in[3];
  const float* Wv  = (const float*)d_in[4];
  const float* Wo  = (const float*)d_in[5];
  const float* qnw = (const float*)d_in[6];
  const float* knw = (const float*)d_in[7];

  char* ws = (char*)d_ws;
  u16*   X    = (u16*)(ws);
  u16*   WT   = (u16*)(ws + 67108864);
  u16*   QKV  = (u16*)(ws + 117440512);
  u16*   VT   = (u16*)(ws + 218103808);
  float2* TAB = (float2*)(ws + 234881024);
  u16*   ATTN = X;
  u16*   WOT  = WT;

  // 1. hidden f32 -> bf16
  k_cvt_bf16<<<(TOK * DM / 4) / 256, 256, 0, stream>>>(hs, X);
  // 2. weight transposes into fused [6144][4096] operand
  k_tr_w<<<dim3(128, 128), dim3(32, 8), 0, stream>>>(Wq, WT, 4096);
  k_tr_w<<<dim3(32, 128),  dim3(32, 8), 0, stream>>>(Wk, WT + (size_t)4096 * 4096, 1024);
  k_tr_w<<<dim3(32, 128),  dim3(32, 8), 0, stream>>>(Wv, WT + (size_t)5120 * 4096, 1024);
  // 3. RoPE table
  k_rope_tab<<<TOK, 64, 0, stream>>>(pos, TAB);
  // 4. QKV GEMM (8-phase 256^2): [8192,4096] x [6144,4096]^T -> bf16 qkv
  k_gemm8<1><<<(8192 / 256) * (6144 / 256), 512, 0, stream>>>(X, WT, QKV, 8192, 6144, 4096);
  // 5. RMSNorm + RoPE in place (q scaled by 1/sqrt(128))
  k_norm_rope<<<TOK * 40 / 4, 256, 0, stream>>>(QKV, TAB, qnw, knw);
  // 6. V transpose to [b][kvh][d][s]
  k_tr_v<<<dim3(4, 16, 128), dim3(32, 8), 0, stream>>>(QKV, VT);
  // 7. Wo transpose (reuses WT region -- safe: after gemm1 in stream order)
  k_tr_w<<<dim3(128, 128), dim3(32, 8), 0, stream>>>(Wo, WOT, 4096);
  // 8. attention -> ATTN (reuses X region -- safe: after gemm1)
  k_attn<<<dim3(16, 8, 16), 256, 0, stream>>>(QKV, VT, ATTN);
  // 9. output projection (8-phase 256^2) -> d_out (f32)
  k_gemm8<0><<<(8192 / 256) * (4096 / 256), 512, 0, stream>>>(ATTN, WOT, d_out, 8192, 4096, 4096);
}

// Round 8
// 895.189 us; speedup vs baseline: 1.1212x; 1.0144x over previous
//
#include <hip/hip_runtime.h>

typedef unsigned short u16;
typedef __attribute__((ext_vector_type(4))) unsigned short u16x4;
typedef __attribute__((ext_vector_type(8))) short short8;
typedef __attribute__((ext_vector_type(4))) float f32x4;

#define DEV static __device__ __forceinline__

constexpr int NB   = 16;
constexpr int S    = 512;
constexpr int DM   = 4096;
constexpr int NH   = 32;
constexpr int NKV  = 8;
constexpr int HD   = 128;
constexpr int TOK  = NB * S;          // 8192
constexpr int NQKV = 6144;            // 4096 q + 1024 k + 1024 v
constexpr float ATT_SCALE = 0.08838834764831845f;  // 1/sqrt(128)

DEV u16 f2b(float f) {
  union { float f; unsigned u; } v; v.f = f;
  unsigned r = v.u + 0x7fffu + ((v.u >> 16) & 1u);
  return (u16)(r >> 16);
}
DEV float b2f(u16 u) {
  union { unsigned u; float f; } v; v.u = ((unsigned)u) << 16;
  return v.f;
}
DEV unsigned cvt_pk_bf16(float lo, float hi) {
  unsigned r;
  asm("v_cvt_pk_bf16_f32 %0, %1, %2" : "=v"(r) : "v"(lo), "v"(hi));
  return r;
}
DEV void async16(const void* g, void* l) {
  __builtin_amdgcn_global_load_lds(
      (const __attribute__((address_space(1))) unsigned int*)g,
      (__attribute__((address_space(3))) unsigned int*)l, 16, 0, 0);
}

// ---------------- f32 -> bf16 convert (hidden states) ----------------
__global__ void k_cvt_bf16(const float* __restrict__ src, u16* __restrict__ dst) {
  int i = (blockIdx.x * 256 + threadIdx.x) * 4;
  const float4 v = *reinterpret_cast<const float4*>(src + i);
  u16x4 o;
  o[0] = f2b(v.x); o[1] = f2b(v.y); o[2] = f2b(v.z); o[3] = f2b(v.w);
  *reinterpret_cast<u16x4*>(dst + i) = o;
}

// ---------------- weight transpose: src[K=4096][ncols] f32 -> dst[ncols][4096] bf16 ----
__global__ void k_tr_w(const float* __restrict__ src, u16* __restrict__ dst, int ncols) {
  __shared__ float tile[32][33];
  int tx = threadIdx.x, ty = threadIdx.y;
  int n0 = blockIdx.x * 32, k0 = blockIdx.y * 32;
#pragma unroll
  for (int i = 0; i < 32; i += 8)
    tile[ty + i][tx] = src[(size_t)(k0 + ty + i) * ncols + n0 + tx];
  __syncthreads();
#pragma unroll
  for (int i = 0; i < 32; i += 8)
    dst[(size_t)(n0 + ty + i) * 4096 + k0 + tx] = f2b(tile[tx][ty + i]);
}

// ---------------- RoPE cos/sin table per (b,s) ----------------
__global__ void k_rope_tab(const int* __restrict__ pos_ids, float2* __restrict__ tab) {
  int t = blockIdx.x;      // 0..8191
  int j = threadIdx.x;     // 0..63
  float pos = (float)pos_ids[t];
  float inv = expf(-(float)j * 0.21586735246819178f);
  float ang = pos * inv;
  float sv, cv;
  sincosf(ang, &sv, &cv);
  tab[t * 64 + j] = make_float2(cv, sv);
}

// ---------------- fused RMSNorm + RoPE, in-place on qkv (q and k heads) ----------------
__global__ void k_norm_rope(u16* __restrict__ qkv, const float2* __restrict__ tab,
                            const float* __restrict__ qw, const float* __restrict__ kw) {
  int wid  = blockIdx.x * 4 + (threadIdx.x >> 6);
  int lane = threadIdx.x & 63;
  int t  = wid / 40;
  int hh = wid - t * 40;
  bool isq = hh < 32;
  u16* base = qkv + (size_t)t * NQKV + (isq ? hh * 128 : 4096 + (hh - 32) * 128);
  float x1 = b2f(base[lane]);
  float x2 = b2f(base[lane + 64]);
  float ss = x1 * x1 + x2 * x2;
#pragma unroll
  for (int m = 1; m < 64; m <<= 1) ss += __shfl_xor(ss, m, 64);
  float r = rsqrtf(ss * (1.0f / 128.0f) + 1e-6f);
  const float* w = isq ? qw : kw;
  float y1 = x1 * r * w[lane];
  float y2 = x2 * r * w[lane + 64];
  float2 cs = tab[t * 64 + lane];
  float o1 = y1 * cs.x - y2 * cs.y;
  float o2 = y2 * cs.x + y1 * cs.y;
  if (isq) { o1 *= ATT_SCALE; o2 *= ATT_SCALE; }
  base[lane]      = f2b(o1);
  base[lane + 64] = f2b(o2);
}

// ---------------- V transpose: qkv v-cols [b][s][kvh][d] -> vt[b][kvh][d][s] ----------
__global__ void k_tr_v(const u16* __restrict__ qkv, u16* __restrict__ vt) {
  __shared__ u16 tile[32][33];
  int bh = blockIdx.z;           // b*8+kvh
  int b = bh >> 3, kvh = bh & 7;
  int d0 = blockIdx.x * 32, s0 = blockIdx.y * 32;
  int tx = threadIdx.x, ty = threadIdx.y;
#pragma unroll
  for (int i = 0; i < 32; i += 8)
    tile[ty + i][tx] = qkv[(size_t)(b * S + s0 + ty + i) * NQKV + 5120 + kvh * 128 + d0 + tx];
  __syncthreads();
#pragma unroll
  for (int i = 0; i < 32; i += 8)
    vt[((size_t)(bh * 128 + d0 + ty + i)) * S + s0 + tx] = tile[tx][ty + i];
}

// =======================================================================================
// 256x256 8-phase GEMM (T2+T3+T4+T5) -- byte-identical to round 7 (frozen).
// =======================================================================================
template <int OUT_BF16>
__global__ __launch_bounds__(512, 2) void k_gemm8(const u16* __restrict__ A,
                                                  const u16* __restrict__ Bm,
                                                  void* __restrict__ Cv,
                                                  int M, int N, int K) {
  __shared__ alignas(16) u16 lds[2][2][256 * 64];   // [buf][A/B][row*64+col]
  const int tid  = threadIdx.x;
  const int lane = tid & 63;
  const int wave = tid >> 6;
  const int r16 = lane & 15, h4 = lane >> 4;
  const int wm = (wave >> 2) * 128, wn = (wave & 3) * 64;

  const int nbx = N >> 8;
  const int nby = M >> 8;
  const int nwg = nby * nbx;
  const int cpx = nwg >> 3;
  const int wg  = blockIdx.x;
  const int gidx = (wg & 7) * cpx + (wg >> 3);
  const int by = gidx % nby;
  const int bx = gidx / nby;
  const int m0 = by << 8, n0 = bx << 8;

  const int NKT = K >> 6;
  const int NIT = NKT >> 1;

  f32x4 acc[8][4] = {};
  short8 af[4][2];
  short8 bfr[4][2];

  auto stage = [&](int s) {
    int ts = s >> 2; if (ts > NKT - 1) ts = NKT - 1;
    const int sel  = s & 3;               // 0:A-h0  1:B-h1  2:A-h1  3:B-h0
    const int isB  = sel & 1;
    const int half = (sel == 1 || sel == 2) ? 1 : 0;
    const u16* G = isB ? Bm : A;
    const int base0 = isB ? n0 : m0;
    u16* lb = &lds[ts & 1][isB][0];
    const int k0 = ts << 6;
#pragma unroll
    for (int j = 0; j < 2; ++j) {
      int c = (j << 9) + tid;             // 0..1023 chunks
      int rl = c >> 3, kcd = c & 7;
      int row = isB ? ((rl & 31) | (half << 5) | ((rl >> 5) << 6))
                    : ((rl & 63) | (half << 6) | ((rl >> 6) << 7));
      int kc = kcd ^ (row & 7);
      async16(G + (size_t)(base0 + row) * K + k0 + (kc << 3),
              lb + row * 64 + (kcd << 3));
    }
  };
  auto ldA = [&](int buf, int mf, int ks) {
    int row = wm + mf * 16 + r16;
    int kc = ((ks << 2) + h4) ^ (r16 & 7);
    return *reinterpret_cast<const short8*>(&lds[buf][0][row * 64 + (kc << 3)]);
  };
  auto ldB = [&](int buf, int nf, int ks) {
    int row = wn + nf * 16 + r16;
    int kc = ((ks << 2) + h4) ^ (r16 & 7);
    return *reinterpret_cast<const short8*>(&lds[buf][1][row * 64 + (kc << 3)]);
  };

#pragma unroll
  for (int s = 0; s < 7; ++s) stage(s);
  asm volatile("s_waitcnt vmcnt(6)" ::: "memory");
  __builtin_amdgcn_s_barrier();

  for (int i = 0; i < NIT; ++i) {
#pragma unroll
    for (int ph = 0; ph < 2; ++ph) {
      const int buf = ph;
#pragma unroll
      for (int g = 0; g < 4; ++g) {
        if (g == 0) {
#pragma unroll
          for (int mf = 0; mf < 4; ++mf)
#pragma unroll
            for (int ks = 0; ks < 2; ++ks) af[mf][ks] = ldA(buf, mf, ks);
#pragma unroll
          for (int nf = 0; nf < 2; ++nf)
#pragma unroll
            for (int ks = 0; ks < 2; ++ks) bfr[nf][ks] = ldB(buf, nf, ks);
        } else if (g == 1) {
#pragma unroll
          for (int nf = 0; nf < 2; ++nf)
#pragma unroll
            for (int ks = 0; ks < 2; ++ks) bfr[2 + nf][ks] = ldB(buf, 2 + nf, ks);
        } else if (g == 2) {
#pragma unroll
          for (int mf = 0; mf < 4; ++mf)
#pragma unroll
            for (int ks = 0; ks < 2; ++ks) af[mf][ks] = ldA(buf, 4 + mf, ks);
        }
        stage(7 + i * 8 + ph * 4 + g);
        __builtin_amdgcn_s_barrier();
        __builtin_amdgcn_s_setprio(1);
        const int mo = (g >= 2) ? 4 : 0;
        const int no = (g == 1 || g == 2) ? 2 : 0;
#pragma unroll
        for (int mf = 0; mf < 4; ++mf)
#pragma unroll
          for (int nf = 0; nf < 2; ++nf)
#pragma unroll
            for (int ks = 0; ks < 2; ++ks)
              acc[mo + mf][no + nf] = __builtin_amdgcn_mfma_f32_16x16x32_bf16(
                  af[mf][ks], bfr[no + nf][ks], acc[mo + mf][no + nf], 0, 0, 0);
        __builtin_amdgcn_s_setprio(0);
        if (g == 3) asm volatile("s_waitcnt vmcnt(6)" ::: "memory");
        __builtin_amdgcn_s_barrier();
      }
    }
  }

  if (OUT_BF16) {
    u16* C = (u16*)Cv;
#pragma unroll
    for (int mf = 0; mf < 8; ++mf)
#pragma unroll
      for (int nf = 0; nf < 4; ++nf)
#pragma unroll
        for (int r = 0; r < 4; ++r) {
          size_t row = m0 + wm + mf * 16 + h4 * 4 + r;
          size_t col = n0 + wn + nf * 16 + r16;
          C[row * N + col] = f2b(acc[mf][nf][r]);
        }
  } else {
    float* C = (float*)Cv;
#pragma unroll
    for (int mf = 0; mf < 8; ++mf)
#pragma unroll
      for (int nf = 0; nf < 4; ++nf)
#pragma unroll
        for (int r = 0; r < 4; ++r) {
          size_t row = m0 + wm + mf * 16 + h4 * 4 + r;
          size_t col = n0 + wn + nf * 16 + r16;
          C[row * N + col] = acc[mf][nf][r];
        }
  }
}

// =======================================================================================
// Flash attention v5: swapped-operand MFMA + cvt_pk-packed P (T12) + defer-max (T13)
// + setprio around MFMA clusters (T5). Staging/barrier structure unchanged from r4-r7.
// =======================================================================================
__global__ __launch_bounds__(256) void k_attn(const u16* __restrict__ qkv,
                                              const u16* __restrict__ vt,
                                              u16* __restrict__ out) {
  __shared__ alignas(16) u16 Klds[2][64 * 128];   // [buf][key][d] swizzled
  __shared__ alignas(16) u16 Vlds[2][128 * 64];   // [buf][d][key] swizzled
  __shared__ alignas(16) u16 Plds[4][2][16 * 64]; // [wave][rf][q(16)][key(64)] swizzled
  const int qt = blockIdx.x, kvh = blockIdx.y, b = blockIdx.z;
  const int tid = threadIdx.x, lane = tid & 63, wave = tid >> 6;
  const int r16 = lane & 15, h4 = lane >> 4;
  const int h = kvh * 4 + wave;
  const int qr0 = qt * 32;

  auto stageKV = [&](int t, int buf) {
    const int k0 = t << 6;
    const u16* kg = qkv + (size_t)(b * S + k0) * NQKV + 4096 + kvh * 128;
#pragma unroll
    for (int it = 0; it < 4; ++it) {
      int c = tid + (it << 8);            // 0..1023 chunks of 16B
      int key = c >> 4, c8 = c & 15;
      int jc = c8 ^ (key & 7);
      async16(kg + (size_t)key * NQKV + jc * 8, &Klds[buf][c * 8]);
    }
    const u16* vg = vt + (size_t)(b * 8 + kvh) * 128 * S + k0;
#pragma unroll
    for (int it = 0; it < 4; ++it) {
      int c = tid + (it << 8);
      int d = c >> 3, c8 = c & 7;
      int jc = c8 ^ (d & 7);
      async16(vg + (size_t)d * S + jc * 8, &Vlds[buf][c * 8]);
    }
  };
  auto ldK = [&](int buf, int f, int s4) {   // A-frag: row = key, kchunk = h4
    int key = f * 16 + r16;
    int idx = (key * 128 + s4 * 32 + h4 * 8) ^ ((key & 7) << 3);
    return *reinterpret_cast<const short8*>(&Klds[buf][idx]);
  };
  auto ldV = [&](int buf, int df, int ks) {  // A-frag: row = d, kchunk(keys) = h4
    int d = df * 16 + r16;
    int idx = (d * 64 + ks * 32 + h4 * 8) ^ ((d & 7) << 3);
    return *reinterpret_cast<const short8*>(&Vlds[buf][idx]);
  };

  // Q fragments as B-operand: col = q-row (r16), kchunk = h4.
  short8 qf[2][4];
#pragma unroll
  for (int rf = 0; rf < 2; ++rf) {
    const u16* qrow = qkv + (size_t)(b * S + qr0 + rf * 16 + r16) * NQKV + h * 128 + h4 * 8;
#pragma unroll
    for (int s4 = 0; s4 < 4; ++s4)
      qf[rf][s4] = *reinterpret_cast<const short8*>(qrow + s4 * 32);
  }

  float mrow[2] = {-INFINITY, -INFINITY};
  float lrow[2] = {0.f, 0.f};
  f32x4 o[2][8] = {};    // O^T frags: o[rf][df], col = q-row, regs = d-sub

  const int ntiles = (qt >> 1) + 1;
  stageKV(0, 0);
  __syncthreads();

  for (int t = 0; t < ntiles; ++t) {
    const int buf = t & 1;
    if (t + 1 < ntiles) stageKV(t + 1, buf ^ 1);
    const int k0 = t << 6;
    const bool diag = (t == ntiles - 1);
    int fa0 = 4, fa1 = 4;
    if (diag) {
      fa0 = ((qr0 - k0 + 15) >> 4) + 1; if (fa0 > 4) fa0 = 4;
      fa1 = ((qr0 - k0 + 31) >> 4) + 1; if (fa1 > 4) fa1 = 4;
    }
    const int ks_act = (fa1 + 1) >> 1;

    // S^T = K Q^T : sacc[rf][f] cols = q-rows, regs = keys (f*16 + h4*4 + r)
    f32x4 sacc[2][4] = {};
    __builtin_amdgcn_s_setprio(1);
#pragma unroll
    for (int f = 0; f < 4; ++f) {
      if (f < fa1) {
        short8 kf[4];
#pragma unroll
        for (int s4 = 0; s4 < 4; ++s4) kf[s4] = ldK(buf, f, s4);
#pragma unroll
        for (int s4 = 0; s4 < 4; ++s4) {
          if (f < fa0)
            sacc[0][f] = __builtin_amdgcn_mfma_f32_16x16x32_bf16(kf[s4], qf[0][s4], sacc[0][f], 0, 0, 0);
          sacc[1][f] = __builtin_amdgcn_mfma_f32_16x16x32_bf16(kf[s4], qf[1][s4], sacc[1][f], 0, 0, 0);
        }
      }
    }
    __builtin_amdgcn_s_setprio(0);
    // causal mask (all frags incl. skipped ones: they become exp()=0)
    if (diag) {
#pragma unroll
      for (int rf = 0; rf < 2; ++rf)
#pragma unroll
        for (int f = 0; f < 4; ++f)
#pragma unroll
          for (int r = 0; r < 4; ++r) {
            int key = k0 + f * 16 + h4 * 4 + r;
            int row = qr0 + rf * 16 + r16;
            if (key > row) sacc[rf][f][r] = -1e30f;
          }
    }
    // online softmax with defer-max (T13): skip rescale when max grows < THR=8
#pragma unroll
    for (int rf = 0; rf < 2; ++rf) {
      float mx = sacc[rf][0][0];
#pragma unroll
      for (int f = 0; f < 4; ++f)
#pragma unroll
        for (int r = 0; r < 4; ++r) mx = fmaxf(mx, sacc[rf][f][r]);
      mx = fmaxf(mx, __shfl_xor(mx, 16, 64));
      mx = fmaxf(mx, __shfl_xor(mx, 32, 64));
      if (!__all(mx - mrow[rf] <= 8.0f)) {
        float mn = fmaxf(mrow[rf], mx);
        float fac = __expf(mrow[rf] - mn);
        mrow[rf] = mn;
        lrow[rf] *= fac;
#pragma unroll
        for (int df = 0; df < 8; ++df)
#pragma unroll
          for (int r = 0; r < 4; ++r) o[rf][df][r] *= fac;
      }
      float psum = 0.f;
#pragma unroll
      for (int f = 0; f < 4; ++f)
#pragma unroll
        for (int r = 0; r < 4; ++r) {
          float p = __expf(sacc[rf][f][r] - mrow[rf]);
          sacc[rf][f][r] = p;
          psum += p;
        }
      psum += __shfl_xor(psum, 16, 64);
      psum += __shfl_xor(psum, 32, 64);
      lrow[rf] += psum;
    }

    // P^T -> per-wave LDS: cvt_pk pairs + b64 writes (4 consecutive keys per write)
#pragma unroll
    for (int rf = 0; rf < 2; ++rf)
#pragma unroll
      for (int f = 0; f < 4; ++f) {
        uint2 w;
        w.x = cvt_pk_bf16(sacc[rf][f][0], sacc[rf][f][1]);
        w.y = cvt_pk_bf16(sacc[rf][f][2], sacc[rf][f][3]);
        int idx = r16 * 64 + ((f * 16 + h4 * 4) ^ ((r16 & 7) << 3));
        *reinterpret_cast<uint2*>(&Plds[wave][rf][idx]) = w;
      }
    // P^T B-frags: col = q = r16, keys ks*32 + h4*8 .. +8
    short8 pf[2][2];
#pragma unroll
    for (int rf = 0; rf < 2; ++rf)
#pragma unroll
      for (int ks = 0; ks < 2; ++ks)
        if (ks < ks_act) {
          int idx = r16 * 64 + ((ks * 32 + h4 * 8) ^ ((r16 & 7) << 3));
          pf[rf][ks] = *reinterpret_cast<const short8*>(&Plds[wave][rf][idx]);
        }
    // O^T += V^T P^T
    __builtin_amdgcn_s_setprio(1);
#pragma unroll
    for (int df = 0; df < 8; ++df)
#pragma unroll
      for (int ks = 0; ks < 2; ++ks)
        if (ks < ks_act) {
          short8 vf = ldV(buf, df, ks);
#pragma unroll
          for (int rf = 0; rf < 2; ++rf)
            o[rf][df] = __builtin_amdgcn_mfma_f32_16x16x32_bf16(vf, pf[rf][ks], o[rf][df], 0, 0, 0);
        }
    __builtin_amdgcn_s_setprio(0);
    __syncthreads();
  }

  // epilogue: lane owns q-row r16 (per rf); packed u16x4 stores
#pragma unroll
  for (int rf = 0; rf < 2; ++rf) {
    float rinv = 1.0f / lrow[rf];
    int row = qr0 + rf * 16 + r16;
    u16* orow = out + (size_t)(b * S + row) * 4096 + h * 128;
#pragma unroll
    for (int df = 0; df < 8; ++df) {
      unsigned p0 = cvt_pk_bf16(o[rf][df][0] * rinv, o[rf][df][1] * rinv);
      unsigned p1 = cvt_pk_bf16(o[rf][df][2] * rinv, o[rf][df][3] * rinv);
      uint2 pk; pk.x = p0; pk.y = p1;
      *reinterpret_cast<uint2*>(orow + df * 16 + h4 * 4) = pk;
    }
  }
}

// ---------------------------------------------------------------------------------------
extern "C" void kernel_launch(void* const* d_in, const int* in_sizes, int n_in,
                              void* d_out, int out_size, void* d_ws, size_t ws_size,
                              hipStream_t stream) {
  const float* hs  = (const float*)d_in[0];
  const int*   pos = (const int*)d_in[1];
  const float* Wq  = (const float*)d_in[2];
  const float* Wk  = (const float*)d_in[3];
  const float* Wv  = (const float*)d_in[4];
  const float* Wo  = (const float*)d_in[5];
  const float* qnw = (const float*)d_in[6];
  const float* knw = (const float*)d_in[7];

  char* ws = (char*)d_ws;
  u16*   X    = (u16*)(ws);
  u16*   WT   = (u16*)(ws + 67108864);
  u16*   QKV  = (u16*)(ws + 117440512);
  u16*   VT   = (u16*)(ws + 218103808);
  float2* TAB = (float2*)(ws + 234881024);
  u16*   ATTN = X;
  u16*   WOT  = WT;

  // 1. hidden f32 -> bf16
  k_cvt_bf16<<<(TOK * DM / 4) / 256, 256, 0, stream>>>(hs, X);
  // 2. weight transposes into fused [6144][4096] operand
  k_tr_w<<<dim3(128, 128), dim3(32, 8), 0, stream>>>(Wq, WT, 4096);
  k_tr_w<<<dim3(32, 128),  dim3(32, 8), 0, stream>>>(Wk, WT + (size_t)4096 * 4096, 1024);
  k_tr_w<<<dim3(32, 128),  dim3(32, 8), 0, stream>>>(Wv, WT + (size_t)5120 * 4096, 1024);
  // 3. RoPE table
  k_rope_tab<<<TOK, 64, 0, stream>>>(pos, TAB);
  // 4. QKV GEMM (8-phase 256^2): [8192,4096] x [6144,4096]^T -> bf16 qkv
  k_gemm8<1><<<(8192 / 256) * (6144 / 256), 512, 0, stream>>>(X, WT, QKV, 8192, 6144, 4096);
  // 5. RMSNorm + RoPE in place (q scaled by 1/sqrt(128))
  k_norm_rope<<<TOK * 40 / 4, 256, 0, stream>>>(QKV, TAB, qnw, knw);
  // 6. V transpose to [b][kvh][d][s]
  k_tr_v<<<dim3(4, 16, 128), dim3(32, 8), 0, stream>>>(QKV, VT);
  // 7. Wo transpose (reuses WT region -- safe: after gemm1 in stream order)
  k_tr_w<<<dim3(128, 128), dim3(32, 8), 0, stream>>>(Wo, WOT, 4096);
  // 8. attention -> ATTN (reuses X region -- safe: after gemm1)
  k_attn<<<dim3(16, 8, 16), 256, 0, stream>>>(QKV, VT, ATTN);
  // 9. output projection (8-phase 256^2) -> d_out (f32)
  k_gemm8<0><<<(8192 / 256) * (4096 / 256), 512, 0, stream>>>(ATTN, WOT, d_out, 8192, 4096, 4096);
}